// Round 11
// baseline (461.204 us; speedup 1.0000x reference)
//
#include <hip/hip_runtime.h>
#include <hip/hip_bf16.h>
#include <math.h>

// EncoderBlock: B=2, S=4096, D_MODEL=768, H=12, dk=64, D_FF=3072.
// Inputs fp32 (mask int32), output fp32. Internal compute bf16 MFMA.
// Round 18: attn 2-chunk software pipeline (T15). Per iteration:
// barrier -> stage(ci+2) -> QK(ci+1) -> softmax+PV(ci). QK(ci+1) MFMA is
// independent of softmax(ci) VALU -> pipes overlap in-wave (was strictly
// serial QK->exp->PV; MFMA 41%/VALU 48% busy, floor=max not sum).
// 3-buffer LDS rotation (48KB, free at 3 blocks/CU); two named st sets
// (stA/stB, 2x-unrolled loop - no runtime indexing). GEMMs = R17
// (2-phase dbuf + slot swizzle).

typedef __hip_bfloat16 bf16;
typedef short short8 __attribute__((ext_vector_type(8)));   // 8 bf16 (4 VGPRs)
typedef short short4v __attribute__((ext_vector_type(4)));  // 4 bf16 (8B)
typedef float f32x4 __attribute__((ext_vector_type(4)));

#define MFMA(A, B, C) __builtin_amdgcn_mfma_f32_16x16x32_bf16(A, B, C, 0, 0, 0)

#if __has_builtin(__builtin_amdgcn_exp2f)
#define EXP2(x) __builtin_amdgcn_exp2f(x)
#else
#define EXP2(x) exp2f(x)
#endif

// register-only cross-lane swaps (gfx950): both operands read+written.
#define PSWAP32(a, b) asm("v_permlane32_swap_b32 %0, %1" : "+v"(a), "+v"(b))
#define PSWAP16(a, b) asm("v_permlane16_swap_b32 %0, %1" : "+v"(a), "+v"(b))

__device__ __forceinline__ unsigned cvt_pk(float lo, float hi) {
  unsigned r;
  asm("v_cvt_pk_bf16_f32 %0, %1, %2" : "=v"(r) : "v"(lo), "v"(hi));
  return r;
}

__device__ __forceinline__ void gl_lds16(const void* g, void* l) {
  __builtin_amdgcn_global_load_lds(
      (__attribute__((address_space(1))) void*)g,
      (__attribute__((address_space(3))) void*)l, 16, 0, 0);
}

__device__ __forceinline__ short f2b(float f) {
  bf16 h = __float2bfloat16(f);
  return *reinterpret_cast<short*>(&h);
}

// ---------------- fused prep ------------------------------------------------
__global__ __launch_bounds__(256)
void prep_all(const float* __restrict__ wq, const float* __restrict__ wk,
              const float* __restrict__ wv, const float* __restrict__ wo,
              const float* __restrict__ w1, const float* __restrict__ w2,
              const float* __restrict__ bq, const float* __restrict__ bk,
              const float* __restrict__ bv, const int* __restrict__ mask,
              bf16* __restrict__ wqkvb, bf16* __restrict__ wob,
              bf16* __restrict__ w1b, bf16* __restrict__ w2b,
              float* __restrict__ bqkv,
              int* __restrict__ pos_g, int* __restrict__ nch_g,
              bf16* __restrict__ kc, bf16* __restrict__ vtc)
{
  const int t = threadIdx.x;
  if (blockIdx.x < 2) {
    const int b = blockIdx.x;
    const int* mb = mask + b * 4096;
    __shared__ int lsum[256];
    int loc = 0;
    int mv[16];
#pragma unroll
    for (int j = 0; j < 16; j++) { mv[j] = mb[t * 16 + j] ? 1 : 0; loc += mv[j]; }
    lsum[t] = loc;
    __syncthreads();
    for (int off = 1; off < 256; off <<= 1) {
      int v = (t >= off) ? lsum[t - off] : 0;
      __syncthreads();
      lsum[t] += v;
      __syncthreads();
    }
    const int nvalid = lsum[255];
    int base = lsum[t] - loc;
#pragma unroll
    for (int j = 0; j < 16; j++) {
      pos_g[b * 4096 + t * 16 + j] = mv[j] ? base : -1;
      if (mv[j]) base++;
    }
    const int npad = (nvalid + 63) & ~63;
    if (t == 0) { nch_g[b * 2] = npad >> 6; nch_g[b * 2 + 1] = npad - nvalid; }
    const int npv = npad - nvalid;
    if (npv > 0) {
      const int krows = 12 * npv;
      const short8 z = {};
      for (int task = t; task < krows * 8; task += 256) {
        const int rr = task >> 3, cc = task & 7;
        const int hh = rr / npv, r = nvalid + rr % npv;
        *(short8*)&kc[(((long)(b * 12 + hh) * 4096) + r) * 64 + cc * 8] = z;
      }
      const int vrows = 12 * 64;
      for (int task = t; task < vrows * npv; task += 256) {
        const int row = task / npv, j = nvalid + task % npv;
        const int hh = row >> 6, d = row & 63;
        vtc[((long)((b * 12 + hh) * 64 + d)) * 4096 + j] = __float2bfloat16(0.f);
      }
    }
    return;
  }
  const int i = (blockIdx.x - 2) * 256 + t;
  const int W = 147456;   // 768*768/4
  const int F = 589824;   // 3072*768/4
  const float* src; bf16* dst; int off;
  if (i < W)          { src = wq; dst = wqkvb;           off = i; }
  else if (i < 2*W)   { src = wk; dst = wqkvb + 589824;  off = i - W; }
  else if (i < 3*W)   { src = wv; dst = wqkvb + 1179648; off = i - 2*W; }
  else if (i < 4*W)   { src = wo; dst = wob;             off = i - 3*W; }
  else if (i < 4*W+F) { src = w1; dst = w1b;             off = i - 4*W; }
  else                { src = w2; dst = w2b;             off = i - 4*W - F; }
  float4 v = ((const float4*)src)[off];
  short4v o;
  o.x = f2b(v.x); o.y = f2b(v.y); o.z = f2b(v.z); o.w = f2b(v.w);
  ((short4v*)dst)[off] = o;
  if (i < 2304)
    bqkv[i] = (i < 768) ? bq[i] : (i < 1536 ? bk[i - 768] : bv[i - 1536]);
}

// ---------------- LayerNorm (scalar alpha/beta, unbiased std) ----------------
template<typename INT>
__global__ __launch_bounds__(256)
void ln_kernel(const INT* __restrict__ x, bf16* __restrict__ out,
               const float* __restrict__ alpha, const float* __restrict__ beta)
{
  const int row = blockIdx.x;
  const long base = (long)row * 768;
  const int t = threadIdx.x;
  float v[3]; float s = 0.f, ss = 0.f;
#pragma unroll
  for (int i = 0; i < 3; i++) {
    v[i] = (float)x[base + t + i * 256];
    s += v[i]; ss += v[i] * v[i];
  }
#pragma unroll
  for (int off = 32; off > 0; off >>= 1) {
    s  += __shfl_down(s, off);
    ss += __shfl_down(ss, off);
  }
  __shared__ float red[8];
  __shared__ float stats[2];
  const int w = t >> 6;
  if ((t & 63) == 0) { red[w] = s; red[4 + w] = ss; }
  __syncthreads();
  if (t == 0) {
    float S  = red[0] + red[1] + red[2] + red[3];
    float SS = red[4] + red[5] + red[6] + red[7];
    float mean = S * (1.f / 768.f);
    float var = fmaxf((SS - 768.f * mean * mean) * (1.f / 767.f), 0.f);
    stats[0] = mean;
    stats[1] = 1.f / (sqrtf(var) + 1e-6f);
  }
  __syncthreads();
  const float mean = stats[0], rinv = stats[1];
  const float a = alpha[0], b = beta[0];
#pragma unroll
  for (int i = 0; i < 3; i++)
    out[base + t + i * 256] = __float2bfloat16(a * (v[i] - mean) * rinv + b);
}

// ---------------- generic GEMM: C = A*W^T + bias, tile TM x 128 --------------
// 2-phase double-buffered K-loop + 16B-slot LDS swizzle (R17).
template<int MODE, int TM, typename RT, typename OUTT>
__global__ __launch_bounds__(256)
void gemm_bt(const bf16* __restrict__ A, const bf16* __restrict__ W,
             const float* __restrict__ bias, const RT* __restrict__ R,
             OUTT* __restrict__ Cout, int M, int N, int K)
{
  constexpr int MI = TM / 32;                 // acc row-tiles per wave (4 or 2)
  __shared__ __align__(16) bf16 sA[2][TM * 32];
  __shared__ __align__(16) bf16 sB[2][128 * 32];
  const int t = threadIdx.x;
  const int w = t >> 6, lane = t & 63;
  const int lr = lane & 15, quad = lane >> 4;
  const int tm = blockIdx.x * TM, tn = blockIdx.y * 128;
  const int wm = (w >> 1) * (MI * 16), wn = (w & 1) * 64;

  const int srow = w * 16 + (lane >> 2);      // 0..63
  const int sq = lane & 3;                    // 16B slot in row
  const int scol = (sq ^ ((srow >> 1) & 3)) * 8;   // pre-swizzled GLOBAL col
  const int soff = srow * 32 + sq * 8;             // linear LDS dest
  const bf16* Ap = A + (long)(tm + srow) * K + scol;
  const bf16* Wp = W + (long)(tn + srow) * K + scol;
  const long half = (long)64 * K;

  auto stage = [&](int kb, int bi) {
    gl_lds16(Ap + kb, &sA[bi][soff]);
    if (TM == 128) gl_lds16(Ap + kb + half, &sA[bi][soff + 64 * 32]);
    gl_lds16(Wp + kb, &sB[bi][soff]);
    gl_lds16(Wp + kb + half, &sB[bi][soff + 64 * 32]);
  };

  const int cQ = (quad ^ ((lr >> 1) & 3)) * 8;

  f32x4 acc[MI][4] = {};

  stage(0, 0);
  int bi = 0;
  for (int kb = 0; kb < K; kb += 32, bi ^= 1) {
    __syncthreads();                    // buf bi staged; prev reads all done
    if (kb + 32 < K) stage(kb + 32, bi ^ 1);
    const bf16* sAb = sA[bi];
    const bf16* sBb = sB[bi];
    short8 af[MI], bfr[4];
#pragma unroll
    for (int i = 0; i < MI; i++)
      af[i] = *(const short8*)&sAb[(wm + i * 16 + lr) * 32 + cQ];
#pragma unroll
    for (int j = 0; j < 4; j++)
      bfr[j] = *(const short8*)&sBb[(wn + j * 16 + lr) * 32 + cQ];
#pragma unroll
    for (int i = 0; i < MI; i++)
#pragma unroll
      for (int j = 0; j < 4; j++)
        acc[i][j] = MFMA(af[i], bfr[j], acc[i][j]);
  }

#pragma unroll
  for (int i = 0; i < MI; i++) {
#pragma unroll
    for (int j = 0; j < 4; j++) {
      const int col = tn + wn + j * 16 + lr;
      const float bv = bias[col];
#pragma unroll
      for (int r = 0; r < 4; r++) {
        const int m = tm + wm + i * 16 + quad * 4 + r;
        float vv = acc[i][j][r] + bv;
        if (MODE == 1) vv = fmaxf(vv, 0.f);
        if (MODE == 4) vv += (float)R[(long)m * N + col];
        Cout[(long)m * N + col] = (OUTT)vv;
      }
    }
  }
}

// ---------------- fused QKV GEMM: N=2304, region-scatter epilogue -----------
__global__ __launch_bounds__(256)
void gemm_qkv(const bf16* __restrict__ A, const bf16* __restrict__ W,
              const float* __restrict__ bias, const int* __restrict__ pos_g,
              bf16* __restrict__ Qo, bf16* __restrict__ Kc, bf16* __restrict__ Vtc)
{
  const int K = 768;
  __shared__ __align__(16) bf16 sA[2][128 * 32];
  __shared__ __align__(16) bf16 sB[2][128 * 32];
  const int t = threadIdx.x;
  const int w = t >> 6, lane = t & 63;
  const int lr = lane & 15, quad = lane >> 4;
  const int tm = blockIdx.x * 128, tn = blockIdx.y * 128;
  const int wm = (w >> 1) * 64, wn = (w & 1) * 64;

  const int srow = w * 16 + (lane >> 2);
  const int sq = lane & 3;
  const int scol = (sq ^ ((srow >> 1) & 3)) * 8;
  const int soff = srow * 32 + sq * 8;
  const bf16* Ap = A + (long)(tm + srow) * K + scol;
  const bf16* Wp = W + (long)(tn + srow) * K + scol;
  const long half = (long)64 * K;

  auto stage = [&](int kb, int bi) {
    gl_lds16(Ap + kb, &sA[bi][soff]);
    gl_lds16(Ap + kb + half, &sA[bi][soff + 64 * 32]);
    gl_lds16(Wp + kb, &sB[bi][soff]);
    gl_lds16(Wp + kb + half, &sB[bi][soff + 64 * 32]);
  };

  const int cQ = (quad ^ ((lr >> 1) & 3)) * 8;

  f32x4 acc[4][4] = {};

  stage(0, 0);
  int bi = 0;
  for (int kb = 0; kb < K; kb += 32, bi ^= 1) {
    __syncthreads();
    if (kb + 32 < K) stage(kb + 32, bi ^ 1);
    const bf16* sAb = sA[bi];
    const bf16* sBb = sB[bi];
    short8 af[4], bfr[4];
#pragma unroll
    for (int i = 0; i < 4; i++)
      af[i] = *(const short8*)&sAb[(wm + i * 16 + lr) * 32 + cQ];
#pragma unroll
    for (int j = 0; j < 4; j++)
      bfr[j] = *(const short8*)&sBb[(wn + j * 16 + lr) * 32 + cQ];
#pragma unroll
    for (int i = 0; i < 4; i++)
#pragma unroll
      for (int j = 0; j < 4; j++)
        acc[i][j] = MFMA(af[i], bfr[j], acc[i][j]);
  }

  const int region = (tn >= 1536) ? 2 : (tn >= 768 ? 1 : 0);  // block-uniform
#pragma unroll
  for (int i = 0; i < 4; i++) {
#pragma unroll
    for (int j = 0; j < 4; j++) {
      const int col = tn + wn + j * 16 + lr;
      const int c768 = col - region * 768;
      const int hh = c768 >> 6, d = c768 & 63;
      const float bv = bias[col];
#pragma unroll
      for (int r = 0; r < 4; r++) {
        const int m = tm + wm + i * 16 + quad * 4 + r;
        const int bb = m >> 12, sdx = m & 4095;
        float vv = acc[i][j][r] + bv;
        if (region == 0) {
          // fold 1/sqrt(dk) AND log2(e) into Q: softmax uses exp2 directly.
          vv *= 0.18033688011112042f;   // 0.125 * log2(e)
          Qo[((long)(bb * 12 + hh) * 4096 + sdx) * 64 + d] = __float2bfloat16(vv);
        } else {
          const int p_ = pos_g[bb * 4096 + sdx];
          if (p_ >= 0) {
            if (region == 1)
              Kc[((long)(bb * 12 + hh) * 4096 + p_) * 64 + d] = __float2bfloat16(vv);
            else
              Vtc[((long)(bb * 12 + hh) * 64 + d) * 4096 + p_] = __float2bfloat16(vv);
          }
        }
      }
    }
  }
}

// ---------------- Flash attention, 2-chunk pipeline (round-18) ---------------
// 128-row q-blocks (grid 32x24), 4 waves, 2 q-tiles/wave (R13 geometry).
// Per step: barrier -> stage(ci+2 -> B[(ci+2)%3]) -> QK(ci+1) -> SM+PV(ci).
// QK(ci+1) MFMA independent of SM(ci) VALU -> co-issue. Buffer safety:
// B[(ci+2)%3]=B[(ci-1)%3]; its last reads (QK(ci) prev step, PV(ci-1) two
// steps ago) complete before this step's barrier. Every staged buffer is
// certified by the NEXT barrier's vmcnt drain before first read.
__global__ __launch_bounds__(256)
void attn_kernel(const bf16* __restrict__ Q, const bf16* __restrict__ Kg,
                 const bf16* __restrict__ Vt,
                 const int* __restrict__ nch_g, bf16* __restrict__ ctx)
{
  __shared__ __align__(16) bf16 sK[3][64 * 64];   // [key][d], swizzled
  __shared__ __align__(16) bf16 sV[3][64 * 64];   // [d][key], swizzled

  const int t = threadIdx.x, w = t >> 6, lane = t & 63;
  const int lr = lane & 15, quad = lane >> 4;
  const int bh = blockIdx.y, b = bh / 12, hh = bh % 12;
  const int qb = blockIdx.x * 128 + w * 32;
  const long bh_s = (long)bh * 4096;
  const int nch = nch_g[b * 2];
  const int npv = nch_g[b * 2 + 1];

  short8 qf[2][2];
#pragma unroll
  for (int qt = 0; qt < 2; qt++) {
    const bf16* qp = Q + (bh_s + qb + qt * 16 + lr) * 64 + quad * 8;
    qf[qt][0] = *(const short8*)qp;
    qf[qt][1] = *(const short8*)(qp + 32);
  }

  short8 ones;
#pragma unroll
  for (int i = 0; i < 8; i++) ones[i] = (short)0x3F80;

  const int rA = w * 16 + (lane >> 3), rB = rA + 8;
  const int c8 = lane & 7;
  const bf16* kA = Kg + (bh_s + rA) * 64 + ((c8 ^ (rA & 7)) << 3);
  const bf16* kB = Kg + (bh_s + rB) * 64 + ((c8 ^ (rB & 7)) << 3);
  const bf16* vA = Vt + ((long)bh * 64 + rA) * 4096 + ((c8 ^ (rA & 7)) << 3);
  const bf16* vB = Vt + ((long)bh * 64 + rB) * 4096 + ((c8 ^ (rB & 7)) << 3);
  const int ldsA = (w * 16) * 64 + lane * 8;       // elems; == base + lane*16B
  const int ldsB = ldsA + 8 * 64;

  const int cA = (quad * 8) ^ ((lr & 7) << 3);     // swizzled read col (elems)

  f32x4 lacc[2] = {};
  f32x4 Ot[4][2] = {};                             // O^T[d-tile][q-tile]

  auto stage = [&](int kc, int s) {
    gl_lds16(kA + (long)kc * 64, &sK[s][ldsA]);
    gl_lds16(kB + (long)kc * 64, &sK[s][ldsB]);
    gl_lds16(vA + kc, &sV[s][ldsA]);
    gl_lds16(vB + kc, &sV[s][ldsB]);
  };

  auto qk = [&](int s, f32x4 (&st)[4][2]) {
    const bf16* Kb = sK[s];
    __builtin_amdgcn_s_setprio(1);
#pragma unroll
    for (int kt = 0; kt < 4; kt++) {
      const int rowb = (kt * 16 + lr) * 64;
      short8 kfa = *(const short8*)&Kb[rowb + cA];
      short8 kfb = *(const short8*)&Kb[rowb + (cA ^ 32)];
      st[kt][0] = {}; st[kt][1] = {};
      st[kt][0] = MFMA(kfa, qf[0][0], st[kt][0]);
      st[kt][0] = MFMA(kfb, qf[0][1], st[kt][0]);
      st[kt][1] = MFMA(kfa, qf[1][0], st[kt][1]);
      st[kt][1] = MFMA(kfb, qf[1][1], st[kt][1]);
    }
    __builtin_amdgcn_s_setprio(0);
  };

  auto sm_pv = [&](int s, f32x4 (&st)[4][2]) {
    const bf16* Vb = sV[s];
    short8 pf[2][2];
#pragma unroll
    for (int qt = 0; qt < 2; qt++) {
      float p[4][4];
#pragma unroll
      for (int kt = 0; kt < 4; kt++)
#pragma unroll
        for (int r = 0; r < 4; r++)
          p[kt][r] = EXP2(st[kt][qt][r]);
      unsigned u00 = cvt_pk(p[0][0], p[0][1]), u01 = cvt_pk(p[0][2], p[0][3]);
      unsigned u10 = cvt_pk(p[1][0], p[1][1]), u11 = cvt_pk(p[1][2], p[1][3]);
      unsigned u20 = cvt_pk(p[2][0], p[2][1]), u21 = cvt_pk(p[2][2], p[2][3]);
      unsigned u30 = cvt_pk(p[3][0], p[3][1]), u31 = cvt_pk(p[3][2], p[3][3]);
      // stage 1: lane5 <-> reg-bit (kt low bit)
      PSWAP32(u00, u10); PSWAP32(u01, u11);
      PSWAP32(u20, u30); PSWAP32(u21, u31);
      // stage 2: lane4 <-> reg-bit
      PSWAP16(u00, u10); PSWAP16(u01, u11);
      PSWAP16(u20, u30); PSWAP16(u21, u31);
      union { unsigned u[4]; short8 s8; } fa, fb;
      fa.u[0] = u00; fa.u[1] = u01; fa.u[2] = u10; fa.u[3] = u11;  // keys 0-31
      fb.u[0] = u20; fb.u[1] = u21; fb.u[2] = u30; fb.u[3] = u31;  // keys 32-63
      pf[qt][0] = fa.s8;
      pf[qt][1] = fb.s8;
    }

    __builtin_amdgcn_s_setprio(1);
#pragma unroll
    for (int dt = 0; dt < 4; dt++) {
      const int rowb = (dt * 16 + lr) * 64;
      short8 vfa = *(const short8*)&Vb[rowb + cA];
      short8 vfb = *(const short8*)&Vb[rowb + (cA ^ 32)];
      Ot[dt][0] = MFMA(vfa, pf[0][0], Ot[dt][0]);
      Ot[dt][0] = MFMA(vfb, pf[0][1], Ot[dt][0]);
      Ot[dt][1] = MFMA(vfa, pf[1][0], Ot[dt][1]);
      Ot[dt][1] = MFMA(vfb, pf[1][1], Ot[dt][1]);
    }
    lacc[0] = MFMA(ones, pf[0][0], lacc[0]);
    lacc[0] = MFMA(ones, pf[0][1], lacc[0]);
    lacc[1] = MFMA(ones, pf[1][0], lacc[1]);
    lacc[1] = MFMA(ones, pf[1][1], lacc[1]);
    __builtin_amdgcn_s_setprio(0);
  };

  f32x4 stA[4][2], stB[4][2];

  // prologue: buf0 staged+certified; buf1 in flight; stA = QK(0).
  stage(0, 0);
  __syncthreads();
  if (nch > 1) stage(64, 1);
  if (nch > 0) qk(0, stA);

  int ci = 0;
  while (ci + 1 < nch) {
    // even step: consume stA(ci), produce stB(ci+1)
    __syncthreads();                          // certifies buf[(ci+1)%3]
    if (ci + 2 < nch) stage((ci + 2) * 64, (ci + 2) % 3);
    qk((ci + 1) % 3, stB);
    sm_pv(ci % 3, stA);
    ci++;
    if (ci + 1 >= nch) break;
    // odd step: consume stB(ci), produce stA(ci+1)
    __syncthreads();
    if (ci + 2 < nch) stage((ci + 2) * 64, (ci + 2) % 3);
    qk((ci + 1) % 3, stA);
    sm_pv(ci % 3, stB);
    ci++;
  }
  if (ci < nch) {                             // tail: last chunk
    __syncthreads();
    if (ci & 1) sm_pv(ci % 3, stB);
    else        sm_pv(ci % 3, stA);
  }

#pragma unroll
  for (int qt = 0; qt < 2; qt++) {
    const float l = lacc[qt][0] - (float)npv;
    const float il = (l > 0.f) ? 1.f / l : 0.f;
    const int q = qb + qt * 16 + lr;
    bf16* cp = ctx + ((long)(b * 4096 + q)) * 768 + hh * 64 + quad * 4;
#pragma unroll
    for (int dt = 0; dt < 4; dt++) {
      short4v ov;
      ov.x = f2b(Ot[dt][qt][0] * il);
      ov.y = f2b(Ot[dt][qt][1] * il);
      ov.z = f2b(Ot[dt][qt][2] * il);
      ov.w = f2b(Ot[dt][qt][3] * il);
      *(short4v*)(cp + dt * 16) = ov;
    }
  }
}

// ---------------------------------------------------------------------------
extern "C" void kernel_launch(void* const* d_in, const int* in_sizes, int n_in,
                              void* d_out, int out_size, void* d_ws, size_t ws_size,
                              hipStream_t stream)
{
  (void)in_sizes; (void)n_in; (void)out_size; (void)ws_size;
  const float* x    = (const float*)d_in[0];
  const int*   mask = (const int*)  d_in[1];
  const float* wq = (const float*)d_in[2];  const float* bq = (const float*)d_in[3];
  const float* wk = (const float*)d_in[4];  const float* bk = (const float*)d_in[5];
  const float* wv = (const float*)d_in[6];  const float* bv = (const float*)d_in[7];
  const float* wo = (const float*)d_in[8];  const float* bo = (const float*)d_in[9];
  const float* w1 = (const float*)d_in[10]; const float* b1 = (const float*)d_in[11];
  const float* w2 = (const float*)d_in[12]; const float* b2 = (const float*)d_in[13];
  const float* alpha1 = (const float*)d_in[14]; const float* beta1 = (const float*)d_in[15];
  const float* alpha2 = (const float*)d_in[16]; const float* beta2 = (const float*)d_in[17];
  float* out = (float*)d_out;

  const long WSZ = (long)768 * 768 * 2;
  const long W1SZ = (long)3072 * 768 * 2;
  const long SZB = (long)8192 * 768 * 2;
  char* ws = (char*)d_ws;
  bf16* wqkvb = (bf16*)(ws);
  bf16* wob = (bf16*)(ws + 3 * WSZ);
  bf16* w1b = (bf16*)(ws + 4 * WSZ);
  bf16* w2b = (bf16*)(ws + 4 * WSZ + W1SZ);
  char* aux = ws + 4 * WSZ + 2 * W1SZ;
  float* bqkv   = (float*)(aux);
  int*   pos_g  = (int*)(aux + 16384);
  int*   nch_g  = (int*)(aux + 81920);
  const long BASE = 16l << 20;
  bf16* h   = (bf16*)(ws + BASE);
  bf16* qws = (bf16*)(ws + BASE + 1 * SZB);
  bf16* kcw = (bf16*)(ws + BASE + 2 * SZB);
  bf16* vtc = (bf16*)(ws + BASE + 3 * SZB);
  bf16* ctx = (bf16*)(ws + BASE + 4 * SZB);
  bf16* x1  = (bf16*)(ws + BASE + 5 * SZB);
  bf16* ff  = qws;

  dim3 blk(256);

  hipLaunchKernelGGL(prep_all, dim3(6914), blk, 0, stream,
                     wq, wk, wv, wo, w1, w2, bq, bk, bv, mask,
                     wqkvb, wob, w1b, w2b, bqkv, pos_g, nch_g, kcw, vtc);

  hipLaunchKernelGGL((ln_kernel<float>), dim3(8192), blk, 0, stream, x, h, alpha1, beta1);
  hipLaunchKernelGGL(gemm_qkv, dim3(64, 18), blk, 0, stream, h, wqkvb, bqkv, pos_g, qws, kcw, vtc);
  hipLaunchKernelGGL(attn_kernel, dim3(32, 24), blk, 0, stream, qws, kcw, vtc, nch_g, ctx);
  hipLaunchKernelGGL((gemm_bt<4, 64, float, bf16>), dim3(128, 6), blk, 0, stream, ctx, wob, bo, x, x1, 8192, 768, 768);
  hipLaunchKernelGGL((ln_kernel<bf16>), dim3(8192), blk, 0, stream, x1, h, alpha2, beta2);
  hipLaunchKernelGGL((gemm_bt<1, 128, float, bf16>), dim3(64, 24), blk, 0, stream, h, w1b, b1, (const float*)nullptr, ff, 8192, 3072, 768);
  hipLaunchKernelGGL((gemm_bt<4, 64, bf16, float>), dim3(128, 6), blk, 0, stream, ff, w2b, b2, x1, out, 8192, 768, 3072);
}

// Round 12
// 419.238 us; speedup vs baseline: 1.1001x; 1.1001x over previous
//
#include <hip/hip_runtime.h>
#include <hip/hip_bf16.h>
#include <math.h>

// EncoderBlock: B=2, S=4096, D_MODEL=768, H=12, dk=64, D_FF=3072.
// Inputs fp32 (mask int32), output fp32. Internal compute bf16 MFMA.
// Round 19: attn pipeline RETRY with cheap state. R18's failure was VGPR
// (168 -> lost a resident block, occ 25->11): two live f32 score sets =
// 64 regs. Fix: producer stage runs softmax EAGERLY, so only packed-bf16
// pf[2][2] (16 regs) crosses the step boundary. Step: barrier ->
// stage(ci+2) -> QK+SM(ci+1)->pf_next -> PV(ci) with pf_cur. PV MFMA is
// independent of QK->SM chain -> scheduler interleaves (the in-wave
// serialization is the 72us bottleneck; no pipe >50%). st transient.
// GEMMs = R17 (2-phase dbuf + slot swizzle).

typedef __hip_bfloat16 bf16;
typedef short short8 __attribute__((ext_vector_type(8)));   // 8 bf16 (4 VGPRs)
typedef short short4v __attribute__((ext_vector_type(4)));  // 4 bf16 (8B)
typedef float f32x4 __attribute__((ext_vector_type(4)));

#define MFMA(A, B, C) __builtin_amdgcn_mfma_f32_16x16x32_bf16(A, B, C, 0, 0, 0)

#if __has_builtin(__builtin_amdgcn_exp2f)
#define EXP2(x) __builtin_amdgcn_exp2f(x)
#else
#define EXP2(x) exp2f(x)
#endif

// register-only cross-lane swaps (gfx950): both operands read+written.
#define PSWAP32(a, b) asm("v_permlane32_swap_b32 %0, %1" : "+v"(a), "+v"(b))
#define PSWAP16(a, b) asm("v_permlane16_swap_b32 %0, %1" : "+v"(a), "+v"(b))

__device__ __forceinline__ unsigned cvt_pk(float lo, float hi) {
  unsigned r;
  asm("v_cvt_pk_bf16_f32 %0, %1, %2" : "=v"(r) : "v"(lo), "v"(hi));
  return r;
}

__device__ __forceinline__ void gl_lds16(const void* g, void* l) {
  __builtin_amdgcn_global_load_lds(
      (__attribute__((address_space(1))) void*)g,
      (__attribute__((address_space(3))) void*)l, 16, 0, 0);
}

__device__ __forceinline__ short f2b(float f) {
  bf16 h = __float2bfloat16(f);
  return *reinterpret_cast<short*>(&h);
}

// ---------------- fused prep ------------------------------------------------
__global__ __launch_bounds__(256)
void prep_all(const float* __restrict__ wq, const float* __restrict__ wk,
              const float* __restrict__ wv, const float* __restrict__ wo,
              const float* __restrict__ w1, const float* __restrict__ w2,
              const float* __restrict__ bq, const float* __restrict__ bk,
              const float* __restrict__ bv, const int* __restrict__ mask,
              bf16* __restrict__ wqkvb, bf16* __restrict__ wob,
              bf16* __restrict__ w1b, bf16* __restrict__ w2b,
              float* __restrict__ bqkv,
              int* __restrict__ pos_g, int* __restrict__ nch_g,
              bf16* __restrict__ kc, bf16* __restrict__ vtc)
{
  const int t = threadIdx.x;
  if (blockIdx.x < 2) {
    const int b = blockIdx.x;
    const int* mb = mask + b * 4096;
    __shared__ int lsum[256];
    int loc = 0;
    int mv[16];
#pragma unroll
    for (int j = 0; j < 16; j++) { mv[j] = mb[t * 16 + j] ? 1 : 0; loc += mv[j]; }
    lsum[t] = loc;
    __syncthreads();
    for (int off = 1; off < 256; off <<= 1) {
      int v = (t >= off) ? lsum[t - off] : 0;
      __syncthreads();
      lsum[t] += v;
      __syncthreads();
    }
    const int nvalid = lsum[255];
    int base = lsum[t] - loc;
#pragma unroll
    for (int j = 0; j < 16; j++) {
      pos_g[b * 4096 + t * 16 + j] = mv[j] ? base : -1;
      if (mv[j]) base++;
    }
    const int npad = (nvalid + 63) & ~63;
    if (t == 0) { nch_g[b * 2] = npad >> 6; nch_g[b * 2 + 1] = npad - nvalid; }
    const int npv = npad - nvalid;
    if (npv > 0) {
      const int krows = 12 * npv;
      const short8 z = {};
      for (int task = t; task < krows * 8; task += 256) {
        const int rr = task >> 3, cc = task & 7;
        const int hh = rr / npv, r = nvalid + rr % npv;
        *(short8*)&kc[(((long)(b * 12 + hh) * 4096) + r) * 64 + cc * 8] = z;
      }
      const int vrows = 12 * 64;
      for (int task = t; task < vrows * npv; task += 256) {
        const int row = task / npv, j = nvalid + task % npv;
        const int hh = row >> 6, d = row & 63;
        vtc[((long)((b * 12 + hh) * 64 + d)) * 4096 + j] = __float2bfloat16(0.f);
      }
    }
    return;
  }
  const int i = (blockIdx.x - 2) * 256 + t;
  const int W = 147456;   // 768*768/4
  const int F = 589824;   // 3072*768/4
  const float* src; bf16* dst; int off;
  if (i < W)          { src = wq; dst = wqkvb;           off = i; }
  else if (i < 2*W)   { src = wk; dst = wqkvb + 589824;  off = i - W; }
  else if (i < 3*W)   { src = wv; dst = wqkvb + 1179648; off = i - 2*W; }
  else if (i < 4*W)   { src = wo; dst = wob;             off = i - 3*W; }
  else if (i < 4*W+F) { src = w1; dst = w1b;             off = i - 4*W; }
  else                { src = w2; dst = w2b;             off = i - 4*W - F; }
  float4 v = ((const float4*)src)[off];
  short4v o;
  o.x = f2b(v.x); o.y = f2b(v.y); o.z = f2b(v.z); o.w = f2b(v.w);
  ((short4v*)dst)[off] = o;
  if (i < 2304)
    bqkv[i] = (i < 768) ? bq[i] : (i < 1536 ? bk[i - 768] : bv[i - 1536]);
}

// ---------------- LayerNorm (scalar alpha/beta, unbiased std) ----------------
template<typename INT>
__global__ __launch_bounds__(256)
void ln_kernel(const INT* __restrict__ x, bf16* __restrict__ out,
               const float* __restrict__ alpha, const float* __restrict__ beta)
{
  const int row = blockIdx.x;
  const long base = (long)row * 768;
  const int t = threadIdx.x;
  float v[3]; float s = 0.f, ss = 0.f;
#pragma unroll
  for (int i = 0; i < 3; i++) {
    v[i] = (float)x[base + t + i * 256];
    s += v[i]; ss += v[i] * v[i];
  }
#pragma unroll
  for (int off = 32; off > 0; off >>= 1) {
    s  += __shfl_down(s, off);
    ss += __shfl_down(ss, off);
  }
  __shared__ float red[8];
  __shared__ float stats[2];
  const int w = t >> 6;
  if ((t & 63) == 0) { red[w] = s; red[4 + w] = ss; }
  __syncthreads();
  if (t == 0) {
    float S  = red[0] + red[1] + red[2] + red[3];
    float SS = red[4] + red[5] + red[6] + red[7];
    float mean = S * (1.f / 768.f);
    float var = fmaxf((SS - 768.f * mean * mean) * (1.f / 767.f), 0.f);
    stats[0] = mean;
    stats[1] = 1.f / (sqrtf(var) + 1e-6f);
  }
  __syncthreads();
  const float mean = stats[0], rinv = stats[1];
  const float a = alpha[0], b = beta[0];
#pragma unroll
  for (int i = 0; i < 3; i++)
    out[base + t + i * 256] = __float2bfloat16(a * (v[i] - mean) * rinv + b);
}

// ---------------- generic GEMM: C = A*W^T + bias, tile TM x 128 --------------
// 2-phase double-buffered K-loop + 16B-slot LDS swizzle (R17).
template<int MODE, int TM, typename RT, typename OUTT>
__global__ __launch_bounds__(256)
void gemm_bt(const bf16* __restrict__ A, const bf16* __restrict__ W,
             const float* __restrict__ bias, const RT* __restrict__ R,
             OUTT* __restrict__ Cout, int M, int N, int K)
{
  constexpr int MI = TM / 32;                 // acc row-tiles per wave (4 or 2)
  __shared__ __align__(16) bf16 sA[2][TM * 32];
  __shared__ __align__(16) bf16 sB[2][128 * 32];
  const int t = threadIdx.x;
  const int w = t >> 6, lane = t & 63;
  const int lr = lane & 15, quad = lane >> 4;
  const int tm = blockIdx.x * TM, tn = blockIdx.y * 128;
  const int wm = (w >> 1) * (MI * 16), wn = (w & 1) * 64;

  const int srow = w * 16 + (lane >> 2);      // 0..63
  const int sq = lane & 3;                    // 16B slot in row
  const int scol = (sq ^ ((srow >> 1) & 3)) * 8;   // pre-swizzled GLOBAL col
  const int soff = srow * 32 + sq * 8;             // linear LDS dest
  const bf16* Ap = A + (long)(tm + srow) * K + scol;
  const bf16* Wp = W + (long)(tn + srow) * K + scol;
  const long half = (long)64 * K;

  auto stage = [&](int kb, int bi) {
    gl_lds16(Ap + kb, &sA[bi][soff]);
    if (TM == 128) gl_lds16(Ap + kb + half, &sA[bi][soff + 64 * 32]);
    gl_lds16(Wp + kb, &sB[bi][soff]);
    gl_lds16(Wp + kb + half, &sB[bi][soff + 64 * 32]);
  };

  const int cQ = (quad ^ ((lr >> 1) & 3)) * 8;

  f32x4 acc[MI][4] = {};

  stage(0, 0);
  int bi = 0;
  for (int kb = 0; kb < K; kb += 32, bi ^= 1) {
    __syncthreads();                    // buf bi staged; prev reads all done
    if (kb + 32 < K) stage(kb + 32, bi ^ 1);
    const bf16* sAb = sA[bi];
    const bf16* sBb = sB[bi];
    short8 af[MI], bfr[4];
#pragma unroll
    for (int i = 0; i < MI; i++)
      af[i] = *(const short8*)&sAb[(wm + i * 16 + lr) * 32 + cQ];
#pragma unroll
    for (int j = 0; j < 4; j++)
      bfr[j] = *(const short8*)&sBb[(wn + j * 16 + lr) * 32 + cQ];
#pragma unroll
    for (int i = 0; i < MI; i++)
#pragma unroll
      for (int j = 0; j < 4; j++)
        acc[i][j] = MFMA(af[i], bfr[j], acc[i][j]);
  }

#pragma unroll
  for (int i = 0; i < MI; i++) {
#pragma unroll
    for (int j = 0; j < 4; j++) {
      const int col = tn + wn + j * 16 + lr;
      const float bv = bias[col];
#pragma unroll
      for (int r = 0; r < 4; r++) {
        const int m = tm + wm + i * 16 + quad * 4 + r;
        float vv = acc[i][j][r] + bv;
        if (MODE == 1) vv = fmaxf(vv, 0.f);
        if (MODE == 4) vv += (float)R[(long)m * N + col];
        Cout[(long)m * N + col] = (OUTT)vv;
      }
    }
  }
}

// ---------------- fused QKV GEMM: N=2304, region-scatter epilogue -----------
__global__ __launch_bounds__(256)
void gemm_qkv(const bf16* __restrict__ A, const bf16* __restrict__ W,
              const float* __restrict__ bias, const int* __restrict__ pos_g,
              bf16* __restrict__ Qo, bf16* __restrict__ Kc, bf16* __restrict__ Vtc)
{
  const int K = 768;
  __shared__ __align__(16) bf16 sA[2][128 * 32];
  __shared__ __align__(16) bf16 sB[2][128 * 32];
  const int t = threadIdx.x;
  const int w = t >> 6, lane = t & 63;
  const int lr = lane & 15, quad = lane >> 4;
  const int tm = blockIdx.x * 128, tn = blockIdx.y * 128;
  const int wm = (w >> 1) * 64, wn = (w & 1) * 64;

  const int srow = w * 16 + (lane >> 2);
  const int sq = lane & 3;
  const int scol = (sq ^ ((srow >> 1) & 3)) * 8;
  const int soff = srow * 32 + sq * 8;
  const bf16* Ap = A + (long)(tm + srow) * K + scol;
  const bf16* Wp = W + (long)(tn + srow) * K + scol;
  const long half = (long)64 * K;

  auto stage = [&](int kb, int bi) {
    gl_lds16(Ap + kb, &sA[bi][soff]);
    gl_lds16(Ap + kb + half, &sA[bi][soff + 64 * 32]);
    gl_lds16(Wp + kb, &sB[bi][soff]);
    gl_lds16(Wp + kb + half, &sB[bi][soff + 64 * 32]);
  };

  const int cQ = (quad ^ ((lr >> 1) & 3)) * 8;

  f32x4 acc[4][4] = {};

  stage(0, 0);
  int bi = 0;
  for (int kb = 0; kb < K; kb += 32, bi ^= 1) {
    __syncthreads();
    if (kb + 32 < K) stage(kb + 32, bi ^ 1);
    const bf16* sAb = sA[bi];
    const bf16* sBb = sB[bi];
    short8 af[4], bfr[4];
#pragma unroll
    for (int i = 0; i < 4; i++)
      af[i] = *(const short8*)&sAb[(wm + i * 16 + lr) * 32 + cQ];
#pragma unroll
    for (int j = 0; j < 4; j++)
      bfr[j] = *(const short8*)&sBb[(wn + j * 16 + lr) * 32 + cQ];
#pragma unroll
    for (int i = 0; i < 4; i++)
#pragma unroll
      for (int j = 0; j < 4; j++)
        acc[i][j] = MFMA(af[i], bfr[j], acc[i][j]);
  }

  const int region = (tn >= 1536) ? 2 : (tn >= 768 ? 1 : 0);  // block-uniform
#pragma unroll
  for (int i = 0; i < 4; i++) {
#pragma unroll
    for (int j = 0; j < 4; j++) {
      const int col = tn + wn + j * 16 + lr;
      const int c768 = col - region * 768;
      const int hh = c768 >> 6, d = c768 & 63;
      const float bv = bias[col];
#pragma unroll
      for (int r = 0; r < 4; r++) {
        const int m = tm + wm + i * 16 + quad * 4 + r;
        const int bb = m >> 12, sdx = m & 4095;
        float vv = acc[i][j][r] + bv;
        if (region == 0) {
          // fold 1/sqrt(dk) AND log2(e) into Q: softmax uses exp2 directly.
          vv *= 0.18033688011112042f;   // 0.125 * log2(e)
          Qo[((long)(bb * 12 + hh) * 4096 + sdx) * 64 + d] = __float2bfloat16(vv);
        } else {
          const int p_ = pos_g[bb * 4096 + sdx];
          if (p_ >= 0) {
            if (region == 1)
              Kc[((long)(bb * 12 + hh) * 4096 + p_) * 64 + d] = __float2bfloat16(vv);
            else
              Vtc[((long)(bb * 12 + hh) * 64 + d) * 4096 + p_] = __float2bfloat16(vv);
          }
        }
      }
    }
  }
}

// ---------------- Flash attention, pf-pipelined (round-19) -------------------
// 128-row q-blocks (grid 32x24), 4 waves, 2 q-tiles/wave (R13 geometry).
// Step ci: barrier -> stage(ci+2) -> QK+SM(ci+1)->pf_next -> PV(ci) w/ pf_cur.
// Only pf (16 VGPR) crosses the step boundary; st is transient in qk_sm.
// Buffer rotation: buf[(ci+2)%3] last read K at step ci-2, V at step ci-1,
// both before this step's barrier. Every staged buffer certified by the
// next barrier before first read.
__global__ __launch_bounds__(256)
void attn_kernel(const bf16* __restrict__ Q, const bf16* __restrict__ Kg,
                 const bf16* __restrict__ Vt,
                 const int* __restrict__ nch_g, bf16* __restrict__ ctx)
{
  __shared__ __align__(16) bf16 sK[3][64 * 64];   // [key][d], swizzled
  __shared__ __align__(16) bf16 sV[3][64 * 64];   // [d][key], swizzled

  const int t = threadIdx.x, w = t >> 6, lane = t & 63;
  const int lr = lane & 15, quad = lane >> 4;
  const int bh = blockIdx.y, b = bh / 12, hh = bh % 12;
  const int qb = blockIdx.x * 128 + w * 32;
  const long bh_s = (long)bh * 4096;
  const int nch = nch_g[b * 2];
  const int npv = nch_g[b * 2 + 1];

  short8 qf[2][2];
#pragma unroll
  for (int qt = 0; qt < 2; qt++) {
    const bf16* qp = Q + (bh_s + qb + qt * 16 + lr) * 64 + quad * 8;
    qf[qt][0] = *(const short8*)qp;
    qf[qt][1] = *(const short8*)(qp + 32);
  }

  short8 ones;
#pragma unroll
  for (int i = 0; i < 8; i++) ones[i] = (short)0x3F80;

  const int rA = w * 16 + (lane >> 3), rB = rA + 8;
  const int c8 = lane & 7;
  const bf16* kA = Kg + (bh_s + rA) * 64 + ((c8 ^ (rA & 7)) << 3);
  const bf16* kB = Kg + (bh_s + rB) * 64 + ((c8 ^ (rB & 7)) << 3);
  const bf16* vA = Vt + ((long)bh * 64 + rA) * 4096 + ((c8 ^ (rA & 7)) << 3);
  const bf16* vB = Vt + ((long)bh * 64 + rB) * 4096 + ((c8 ^ (rB & 7)) << 3);
  const int ldsA = (w * 16) * 64 + lane * 8;       // elems; == base + lane*16B
  const int ldsB = ldsA + 8 * 64;

  const int cA = (quad * 8) ^ ((lr & 7) << 3);     // swizzled read col (elems)

  f32x4 lacc[2] = {};
  f32x4 Ot[4][2] = {};                             // O^T[d-tile][q-tile]

  auto stage = [&](int kc, int s) {
    gl_lds16(kA + (long)kc * 64, &sK[s][ldsA]);
    gl_lds16(kB + (long)kc * 64, &sK[s][ldsB]);
    gl_lds16(vA + kc, &sV[s][ldsA]);
    gl_lds16(vB + kc, &sV[s][ldsB]);
  };

  // producer: QK + softmax for one chunk -> packed-bf16 pf (st transient).
  auto qk_sm = [&](int s, short8 (&pf)[2][2]) {
    const bf16* Kb = sK[s];
    f32x4 st[4][2];
    __builtin_amdgcn_s_setprio(1);
#pragma unroll
    for (int kt = 0; kt < 4; kt++) {
      const int rowb = (kt * 16 + lr) * 64;
      short8 kfa = *(const short8*)&Kb[rowb + cA];
      short8 kfb = *(const short8*)&Kb[rowb + (cA ^ 32)];
      st[kt][0] = {}; st[kt][1] = {};
      st[kt][0] = MFMA(kfa, qf[0][0], st[kt][0]);
      st[kt][0] = MFMA(kfb, qf[0][1], st[kt][0]);
      st[kt][1] = MFMA(kfa, qf[1][0], st[kt][1]);
      st[kt][1] = MFMA(kfb, qf[1][1], st[kt][1]);
    }
    __builtin_amdgcn_s_setprio(0);
#pragma unroll
    for (int qt = 0; qt < 2; qt++) {
      float p[4][4];
#pragma unroll
      for (int kt = 0; kt < 4; kt++)
#pragma unroll
        for (int r = 0; r < 4; r++)
          p[kt][r] = EXP2(st[kt][qt][r]);
      unsigned u00 = cvt_pk(p[0][0], p[0][1]), u01 = cvt_pk(p[0][2], p[0][3]);
      unsigned u10 = cvt_pk(p[1][0], p[1][1]), u11 = cvt_pk(p[1][2], p[1][3]);
      unsigned u20 = cvt_pk(p[2][0], p[2][1]), u21 = cvt_pk(p[2][2], p[2][3]);
      unsigned u30 = cvt_pk(p[3][0], p[3][1]), u31 = cvt_pk(p[3][2], p[3][3]);
      // stage 1: lane5 <-> reg-bit (kt low bit)
      PSWAP32(u00, u10); PSWAP32(u01, u11);
      PSWAP32(u20, u30); PSWAP32(u21, u31);
      // stage 2: lane4 <-> reg-bit
      PSWAP16(u00, u10); PSWAP16(u01, u11);
      PSWAP16(u20, u30); PSWAP16(u21, u31);
      union { unsigned u[4]; short8 s8; } fa, fb;
      fa.u[0] = u00; fa.u[1] = u01; fa.u[2] = u10; fa.u[3] = u11;  // keys 0-31
      fb.u[0] = u20; fb.u[1] = u21; fb.u[2] = u30; fb.u[3] = u31;  // keys 32-63
      pf[qt][0] = fa.s8;
      pf[qt][1] = fb.s8;
    }
  };

  // consumer: PV + denominator for one chunk from its pf.
  auto pv = [&](int s, short8 (&pf)[2][2]) {
    const bf16* Vb = sV[s];
    __builtin_amdgcn_s_setprio(1);
#pragma unroll
    for (int dt = 0; dt < 4; dt++) {
      const int rowb = (dt * 16 + lr) * 64;
      short8 vfa = *(const short8*)&Vb[rowb + cA];
      short8 vfb = *(const short8*)&Vb[rowb + (cA ^ 32)];
      Ot[dt][0] = MFMA(vfa, pf[0][0], Ot[dt][0]);
      Ot[dt][0] = MFMA(vfb, pf[0][1], Ot[dt][0]);
      Ot[dt][1] = MFMA(vfa, pf[1][0], Ot[dt][1]);
      Ot[dt][1] = MFMA(vfb, pf[1][1], Ot[dt][1]);
    }
    lacc[0] = MFMA(ones, pf[0][0], lacc[0]);
    lacc[0] = MFMA(ones, pf[0][1], lacc[0]);
    lacc[1] = MFMA(ones, pf[1][0], lacc[1]);
    lacc[1] = MFMA(ones, pf[1][1], lacc[1]);
    __builtin_amdgcn_s_setprio(0);
  };

  short8 pfA[2][2], pfB[2][2];

  // prologue: buf0 staged+certified; buf1 in flight; pfA = SM(QK(0)).
  stage(0, 0);
  __syncthreads();
  if (nch > 1) stage(64, 1);
  if (nch > 0) qk_sm(0, pfA);

  int ci = 0;
  while (ci + 1 < nch) {
    // even step: produce pfB(ci+1), consume pfA(ci)
    __syncthreads();                          // certifies buf[(ci+1)%3]
    if (ci + 2 < nch) stage((ci + 2) * 64, (ci + 2) % 3);
    qk_sm((ci + 1) % 3, pfB);
    pv(ci % 3, pfA);
    ci++;
    if (ci + 1 >= nch) break;
    // odd step: produce pfA(ci+1), consume pfB(ci)
    __syncthreads();
    if (ci + 2 < nch) stage((ci + 2) * 64, (ci + 2) % 3);
    qk_sm((ci + 1) % 3, pfA);
    pv(ci % 3, pfB);
    ci++;
  }
  if (ci < nch) {                             // tail: PV of last chunk
    if (ci & 1) pv(ci % 3, pfB);
    else        pv(ci % 3, pfA);
  }

#pragma unroll
  for (int qt = 0; qt < 2; qt++) {
    const float l = lacc[qt][0] - (float)npv;
    const float il = (l > 0.f) ? 1.f / l : 0.f;
    const int q = qb + qt * 16 + lr;
    bf16* cp = ctx + ((long)(b * 4096 + q)) * 768 + hh * 64 + quad * 4;
#pragma unroll
    for (int dt = 0; dt < 4; dt++) {
      short4v ov;
      ov.x = f2b(Ot[dt][qt][0] * il);
      ov.y = f2b(Ot[dt][qt][1] * il);
      ov.z = f2b(Ot[dt][qt][2] * il);
      ov.w = f2b(Ot[dt][qt][3] * il);
      *(short4v*)(cp + dt * 16) = ov;
    }
  }
}

// ---------------------------------------------------------------------------
extern "C" void kernel_launch(void* const* d_in, const int* in_sizes, int n_in,
                              void* d_out, int out_size, void* d_ws, size_t ws_size,
                              hipStream_t stream)
{
  (void)in_sizes; (void)n_in; (void)out_size; (void)ws_size;
  const float* x    = (const float*)d_in[0];
  const int*   mask = (const int*)  d_in[1];
  const float* wq = (const float*)d_in[2];  const float* bq = (const float*)d_in[3];
  const float* wk = (const float*)d_in[4];  const float* bk = (const float*)d_in[5];
  const float* wv = (const float*)d_in[6];  const float* bv = (const float*)d_in[7];
  const float* wo = (const float*)d_in[8];  const float* bo = (const float*)d_in[9];
  const float* w1 = (const float*)d_in[10]; const float* b1 = (const float*)d_in[11];
  const float* w2 = (const float*)d_in[12]; const float* b2 = (const float*)d_in[13];
  const float* alpha1 = (const float*)d_in[14]; const float* beta1 = (const float*)d_in[15];
  const float* alpha2 = (const float*)d_in[16]; const float* beta2 = (const float*)d_in[17];
  float* out = (float*)d_out;

  const long WSZ = (long)768 * 768 * 2;
  const long W1SZ = (long)3072 * 768 * 2;
  const long SZB = (long)8192 * 768 * 2;
  char* ws = (char*)d_ws;
  bf16* wqkvb = (bf16*)(ws);
  bf16* wob = (bf16*)(ws + 3 * WSZ);
  bf16* w1b = (bf16*)(ws + 4 * WSZ);
  bf16* w2b = (bf16*)(ws + 4 * WSZ + W1SZ);
  char* aux = ws + 4 * WSZ + 2 * W1SZ;
  float* bqkv   = (float*)(aux);
  int*   pos_g  = (int*)(aux + 16384);
  int*   nch_g  = (int*)(aux + 81920);
  const long BASE = 16l << 20;
  bf16* h   = (bf16*)(ws + BASE);
  bf16* qws = (bf16*)(ws + BASE + 1 * SZB);
  bf16* kcw = (bf16*)(ws + BASE + 2 * SZB);
  bf16* vtc = (bf16*)(ws + BASE + 3 * SZB);
  bf16* ctx = (bf16*)(ws + BASE + 4 * SZB);
  bf16* x1  = (bf16*)(ws + BASE + 5 * SZB);
  bf16* ff  = qws;

  dim3 blk(256);

  hipLaunchKernelGGL(prep_all, dim3(6914), blk, 0, stream,
                     wq, wk, wv, wo, w1, w2, bq, bk, bv, mask,
                     wqkvb, wob, w1b, w2b, bqkv, pos_g, nch_g, kcw, vtc);

  hipLaunchKernelGGL((ln_kernel<float>), dim3(8192), blk, 0, stream, x, h, alpha1, beta1);
  hipLaunchKernelGGL(gemm_qkv, dim3(64, 18), blk, 0, stream, h, wqkvb, bqkv, pos_g, qws, kcw, vtc);
  hipLaunchKernelGGL(attn_kernel, dim3(32, 24), blk, 0, stream, qws, kcw, vtc, nch_g, ctx);
  hipLaunchKernelGGL((gemm_bt<4, 64, float, bf16>), dim3(128, 6), blk, 0, stream, ctx, wob, bo, x, x1, 8192, 768, 768);
  hipLaunchKernelGGL((ln_kernel<bf16>), dim3(8192), blk, 0, stream, x1, h, alpha2, beta2);
  hipLaunchKernelGGL((gemm_bt<1, 128, float, bf16>), dim3(64, 24), blk, 0, stream, h, w1b, b1, (const float*)nullptr, ff, 8192, 3072, 768);
  hipLaunchKernelGGL((gemm_bt<4, 64, bf16, float>), dim3(128, 6), blk, 0, stream, ff, w2b, b2, x1, out, 8192, 768, 3072);
}

// Round 13
// 379.641 us; speedup vs baseline: 1.2148x; 1.1043x over previous
//
#include <hip/hip_runtime.h>
#include <hip/hip_bf16.h>
#include <math.h>

// EncoderBlock: B=2, S=4096, D_MODEL=768, H=12, dk=64, D_FF=3072.
// Inputs fp32 (mask int32), output fp32. Internal compute bf16 MFMA.
// Round 20: attn reverted to R13 (both pipeline attempts regressed:
// in-order issue + compiler didn't interleave across lambda bounds).
// GEMM: gemm_bt parametrized by BK; O-proj & FFN2 (TM=64) run BK=64 —
// halves K-steps/barriers (FFN2 96->48) with NO occupancy loss (LDS
// 48KB = 3 resident = grid limit). Bank math at BK=64: row stride 128B
// wraps all 32 banks -> swizzle slot^=(row&7) over 8 slots -> 2-way
// (free). BK=32 path bit-identical to R17 (qkv/FFN1 untouched).

typedef __hip_bfloat16 bf16;
typedef short short8 __attribute__((ext_vector_type(8)));   // 8 bf16 (4 VGPRs)
typedef short short4v __attribute__((ext_vector_type(4)));  // 4 bf16 (8B)
typedef float f32x4 __attribute__((ext_vector_type(4)));

#define MFMA(A, B, C) __builtin_amdgcn_mfma_f32_16x16x32_bf16(A, B, C, 0, 0, 0)

#if __has_builtin(__builtin_amdgcn_exp2f)
#define EXP2(x) __builtin_amdgcn_exp2f(x)
#else
#define EXP2(x) exp2f(x)
#endif

// register-only cross-lane swaps (gfx950): both operands read+written.
#define PSWAP32(a, b) asm("v_permlane32_swap_b32 %0, %1" : "+v"(a), "+v"(b))
#define PSWAP16(a, b) asm("v_permlane16_swap_b32 %0, %1" : "+v"(a), "+v"(b))

__device__ __forceinline__ unsigned cvt_pk(float lo, float hi) {
  unsigned r;
  asm("v_cvt_pk_bf16_f32 %0, %1, %2" : "=v"(r) : "v"(lo), "v"(hi));
  return r;
}

__device__ __forceinline__ void gl_lds16(const void* g, void* l) {
  __builtin_amdgcn_global_load_lds(
      (__attribute__((address_space(1))) void*)g,
      (__attribute__((address_space(3))) void*)l, 16, 0, 0);
}

__device__ __forceinline__ short f2b(float f) {
  bf16 h = __float2bfloat16(f);
  return *reinterpret_cast<short*>(&h);
}

// ---------------- fused prep ------------------------------------------------
__global__ __launch_bounds__(256)
void prep_all(const float* __restrict__ wq, const float* __restrict__ wk,
              const float* __restrict__ wv, const float* __restrict__ wo,
              const float* __restrict__ w1, const float* __restrict__ w2,
              const float* __restrict__ bq, const float* __restrict__ bk,
              const float* __restrict__ bv, const int* __restrict__ mask,
              bf16* __restrict__ wqkvb, bf16* __restrict__ wob,
              bf16* __restrict__ w1b, bf16* __restrict__ w2b,
              float* __restrict__ bqkv,
              int* __restrict__ pos_g, int* __restrict__ nch_g,
              bf16* __restrict__ kc, bf16* __restrict__ vtc)
{
  const int t = threadIdx.x;
  if (blockIdx.x < 2) {
    const int b = blockIdx.x;
    const int* mb = mask + b * 4096;
    __shared__ int lsum[256];
    int loc = 0;
    int mv[16];
#pragma unroll
    for (int j = 0; j < 16; j++) { mv[j] = mb[t * 16 + j] ? 1 : 0; loc += mv[j]; }
    lsum[t] = loc;
    __syncthreads();
    for (int off = 1; off < 256; off <<= 1) {
      int v = (t >= off) ? lsum[t - off] : 0;
      __syncthreads();
      lsum[t] += v;
      __syncthreads();
    }
    const int nvalid = lsum[255];
    int base = lsum[t] - loc;
#pragma unroll
    for (int j = 0; j < 16; j++) {
      pos_g[b * 4096 + t * 16 + j] = mv[j] ? base : -1;
      if (mv[j]) base++;
    }
    const int npad = (nvalid + 63) & ~63;
    if (t == 0) { nch_g[b * 2] = npad >> 6; nch_g[b * 2 + 1] = npad - nvalid; }
    const int npv = npad - nvalid;
    if (npv > 0) {
      const int krows = 12 * npv;
      const short8 z = {};
      for (int task = t; task < krows * 8; task += 256) {
        const int rr = task >> 3, cc = task & 7;
        const int hh = rr / npv, r = nvalid + rr % npv;
        *(short8*)&kc[(((long)(b * 12 + hh) * 4096) + r) * 64 + cc * 8] = z;
      }
      const int vrows = 12 * 64;
      for (int task = t; task < vrows * npv; task += 256) {
        const int row = task / npv, j = nvalid + task % npv;
        const int hh = row >> 6, d = row & 63;
        vtc[((long)((b * 12 + hh) * 64 + d)) * 4096 + j] = __float2bfloat16(0.f);
      }
    }
    return;
  }
  const int i = (blockIdx.x - 2) * 256 + t;
  const int W = 147456;   // 768*768/4
  const int F = 589824;   // 3072*768/4
  const float* src; bf16* dst; int off;
  if (i < W)          { src = wq; dst = wqkvb;           off = i; }
  else if (i < 2*W)   { src = wk; dst = wqkvb + 589824;  off = i - W; }
  else if (i < 3*W)   { src = wv; dst = wqkvb + 1179648; off = i - 2*W; }
  else if (i < 4*W)   { src = wo; dst = wob;             off = i - 3*W; }
  else if (i < 4*W+F) { src = w1; dst = w1b;             off = i - 4*W; }
  else                { src = w2; dst = w2b;             off = i - 4*W - F; }
  float4 v = ((const float4*)src)[off];
  short4v o;
  o.x = f2b(v.x); o.y = f2b(v.y); o.z = f2b(v.z); o.w = f2b(v.w);
  ((short4v*)dst)[off] = o;
  if (i < 2304)
    bqkv[i] = (i < 768) ? bq[i] : (i < 1536 ? bk[i - 768] : bv[i - 1536]);
}

// ---------------- LayerNorm (scalar alpha/beta, unbiased std) ----------------
template<typename INT>
__global__ __launch_bounds__(256)
void ln_kernel(const INT* __restrict__ x, bf16* __restrict__ out,
               const float* __restrict__ alpha, const float* __restrict__ beta)
{
  const int row = blockIdx.x;
  const long base = (long)row * 768;
  const int t = threadIdx.x;
  float v[3]; float s = 0.f, ss = 0.f;
#pragma unroll
  for (int i = 0; i < 3; i++) {
    v[i] = (float)x[base + t + i * 256];
    s += v[i]; ss += v[i] * v[i];
  }
#pragma unroll
  for (int off = 32; off > 0; off >>= 1) {
    s  += __shfl_down(s, off);
    ss += __shfl_down(ss, off);
  }
  __shared__ float red[8];
  __shared__ float stats[2];
  const int w = t >> 6;
  if ((t & 63) == 0) { red[w] = s; red[4 + w] = ss; }
  __syncthreads();
  if (t == 0) {
    float S  = red[0] + red[1] + red[2] + red[3];
    float SS = red[4] + red[5] + red[6] + red[7];
    float mean = S * (1.f / 768.f);
    float var = fmaxf((SS - 768.f * mean * mean) * (1.f / 767.f), 0.f);
    stats[0] = mean;
    stats[1] = 1.f / (sqrtf(var) + 1e-6f);
  }
  __syncthreads();
  const float mean = stats[0], rinv = stats[1];
  const float a = alpha[0], b = beta[0];
#pragma unroll
  for (int i = 0; i < 3; i++)
    out[base + t + i * 256] = __float2bfloat16(a * (v[i] - mean) * rinv + b);
}

// ---------------- generic GEMM: C = A*W^T + bias, tile TM x 128, BK param ----
// 2-phase double-buffered K-loop + per-BK slot swizzle.
// BK=32: slots=4, swz=(row>>1)&3 (row stride 64B). BK=64: slots=8,
// swz=row&7 (row stride 128B wraps banks). Both give 2-way (free) reads.
template<int MODE, int TM, int BK, typename RT, typename OUTT>
__global__ __launch_bounds__(256)
void gemm_bt(const bf16* __restrict__ A, const bf16* __restrict__ W,
             const float* __restrict__ bias, const RT* __restrict__ R,
             OUTT* __restrict__ Cout, int M, int N, int K)
{
  constexpr int MI = TM / 32;            // acc row-tiles per wave (4 or 2)
  constexpr int SLOTS = BK / 8;          // 16B slots per LDS row
  constexpr int RPC = 2048 / BK;         // rows covered per gl_lds call
  constexpr int KS = BK / 32;            // k-slices per K-step
  __shared__ __align__(16) bf16 sA[2][TM * BK];
  __shared__ __align__(16) bf16 sB[2][128 * BK];
  const int t = threadIdx.x;
  const int w = t >> 6, lane = t & 63;
  const int lr = lane & 15, quad = lane >> 4;
  const int tm = blockIdx.x * TM, tn = blockIdx.y * 128;
  const int wm = (w >> 1) * (MI * 16), wn = (w & 1) * 64;

  const int srow = t / SLOTS;            // 0..RPC-1
  const int sq = t % SLOTS;
  const int swzs = (BK == 64) ? (srow & 7) : ((srow >> 1) & 3);
  const int scol = (sq ^ swzs) * 8;      // pre-swizzled GLOBAL col
  const int soff = srow * BK + sq * 8;   // linear LDS dest (= base + lane*16B)
  const bf16* Ap = A + (long)(tm + srow) * K + scol;
  const bf16* Wp = W + (long)(tn + srow) * K + scol;

  auto stage = [&](int kb, int bi) {
#pragma unroll
    for (int r0 = 0; r0 < TM / RPC; r0++)
      gl_lds16(Ap + kb + (long)r0 * RPC * K, &sA[bi][soff + r0 * RPC * BK]);
#pragma unroll
    for (int r0 = 0; r0 < 128 / RPC; r0++)
      gl_lds16(Wp + kb + (long)r0 * RPC * K, &sB[bi][soff + r0 * RPC * BK]);
  };

  // read-side swizzle bits: fragment rows = base(≡0 mod 16) + lr
  const int swzr = (BK == 64) ? (lr & 7) : ((lr >> 1) & 3);

  f32x4 acc[MI][4] = {};

  stage(0, 0);
  int bi = 0;
  for (int kb = 0; kb < K; kb += BK, bi ^= 1) {
    __syncthreads();                    // buf bi staged; prev reads all done
    if (kb + BK < K) stage(kb + BK, bi ^ 1);
    const bf16* sAb = sA[bi];
    const bf16* sBb = sB[bi];
#pragma unroll
    for (int ks = 0; ks < KS; ks++) {
      const int cQ = (((ks << 2) + quad) ^ swzr) * 8;
      short8 af[MI], bfr[4];
#pragma unroll
      for (int i = 0; i < MI; i++)
        af[i] = *(const short8*)&sAb[(wm + i * 16 + lr) * BK + cQ];
#pragma unroll
      for (int j = 0; j < 4; j++)
        bfr[j] = *(const short8*)&sBb[(wn + j * 16 + lr) * BK + cQ];
#pragma unroll
      for (int i = 0; i < MI; i++)
#pragma unroll
        for (int j = 0; j < 4; j++)
          acc[i][j] = MFMA(af[i], bfr[j], acc[i][j]);
    }
  }

#pragma unroll
  for (int i = 0; i < MI; i++) {
#pragma unroll
    for (int j = 0; j < 4; j++) {
      const int col = tn + wn + j * 16 + lr;
      const float bv = bias[col];
#pragma unroll
      for (int r = 0; r < 4; r++) {
        const int m = tm + wm + i * 16 + quad * 4 + r;
        float vv = acc[i][j][r] + bv;
        if (MODE == 1) vv = fmaxf(vv, 0.f);
        if (MODE == 4) vv += (float)R[(long)m * N + col];
        Cout[(long)m * N + col] = (OUTT)vv;
      }
    }
  }
}

// ---------------- fused QKV GEMM: N=2304, region-scatter epilogue -----------
// 2-phase loop + BK=32 slot swizzle (R17, verified).
__global__ __launch_bounds__(256)
void gemm_qkv(const bf16* __restrict__ A, const bf16* __restrict__ W,
              const float* __restrict__ bias, const int* __restrict__ pos_g,
              bf16* __restrict__ Qo, bf16* __restrict__ Kc, bf16* __restrict__ Vtc)
{
  const int K = 768;
  __shared__ __align__(16) bf16 sA[2][128 * 32];
  __shared__ __align__(16) bf16 sB[2][128 * 32];
  const int t = threadIdx.x;
  const int w = t >> 6, lane = t & 63;
  const int lr = lane & 15, quad = lane >> 4;
  const int tm = blockIdx.x * 128, tn = blockIdx.y * 128;
  const int wm = (w >> 1) * 64, wn = (w & 1) * 64;

  const int srow = t >> 2;
  const int sq = t & 3;
  const int scol = (sq ^ ((srow >> 1) & 3)) * 8;
  const int soff = srow * 32 + sq * 8;
  const bf16* Ap = A + (long)(tm + srow) * K + scol;
  const bf16* Wp = W + (long)(tn + srow) * K + scol;
  const long half = (long)64 * K;

  auto stage = [&](int kb, int bi) {
    gl_lds16(Ap + kb, &sA[bi][soff]);
    gl_lds16(Ap + kb + half, &sA[bi][soff + 64 * 32]);
    gl_lds16(Wp + kb, &sB[bi][soff]);
    gl_lds16(Wp + kb + half, &sB[bi][soff + 64 * 32]);
  };

  const int cQ = (quad ^ ((lr >> 1) & 3)) * 8;

  f32x4 acc[4][4] = {};

  stage(0, 0);
  int bi = 0;
  for (int kb = 0; kb < K; kb += 32, bi ^= 1) {
    __syncthreads();
    if (kb + 32 < K) stage(kb + 32, bi ^ 1);
    const bf16* sAb = sA[bi];
    const bf16* sBb = sB[bi];
    short8 af[4], bfr[4];
#pragma unroll
    for (int i = 0; i < 4; i++)
      af[i] = *(const short8*)&sAb[(wm + i * 16 + lr) * 32 + cQ];
#pragma unroll
    for (int j = 0; j < 4; j++)
      bfr[j] = *(const short8*)&sBb[(wn + j * 16 + lr) * 32 + cQ];
#pragma unroll
    for (int i = 0; i < 4; i++)
#pragma unroll
      for (int j = 0; j < 4; j++)
        acc[i][j] = MFMA(af[i], bfr[j], acc[i][j]);
  }

  const int region = (tn >= 1536) ? 2 : (tn >= 768 ? 1 : 0);  // block-uniform
#pragma unroll
  for (int i = 0; i < 4; i++) {
#pragma unroll
    for (int j = 0; j < 4; j++) {
      const int col = tn + wn + j * 16 + lr;
      const int c768 = col - region * 768;
      const int hh = c768 >> 6, d = c768 & 63;
      const float bv = bias[col];
#pragma unroll
      for (int r = 0; r < 4; r++) {
        const int m = tm + wm + i * 16 + quad * 4 + r;
        const int bb = m >> 12, sdx = m & 4095;
        float vv = acc[i][j][r] + bv;
        if (region == 0) {
          // fold 1/sqrt(dk) AND log2(e) into Q: softmax uses exp2 directly.
          vv *= 0.18033688011112042f;   // 0.125 * log2(e)
          Qo[((long)(bb * 12 + hh) * 4096 + sdx) * 64 + d] = __float2bfloat16(vv);
        } else {
          const int p_ = pos_g[bb * 4096 + sdx];
          if (p_ >= 0) {
            if (region == 1)
              Kc[((long)(bb * 12 + hh) * 4096 + p_) * 64 + d] = __float2bfloat16(vv);
            else
              Vtc[((long)(bb * 12 + hh) * 64 + d) * 4096 + p_] = __float2bfloat16(vv);
          }
        }
      }
    }
  }
}

// ---------------- Flash attention, in-register softmax (R13, verified) ------
__global__ __launch_bounds__(256)
void attn_kernel(const bf16* __restrict__ Q, const bf16* __restrict__ Kg,
                 const bf16* __restrict__ Vt,
                 const int* __restrict__ nch_g, bf16* __restrict__ ctx)
{
  __shared__ __align__(16) bf16 sK[2][64 * 64];   // [key][d], swizzled
  __shared__ __align__(16) bf16 sV[2][64 * 64];   // [d][key], swizzled

  const int t = threadIdx.x, w = t >> 6, lane = t & 63;
  const int lr = lane & 15, quad = lane >> 4;
  const int bh = blockIdx.y, b = bh / 12, hh = bh % 12;
  const int qb = blockIdx.x * 128 + w * 32;
  const long bh_s = (long)bh * 4096;
  const int nch = nch_g[b * 2];
  const int npv = nch_g[b * 2 + 1];

  short8 qf[2][2];
#pragma unroll
  for (int qt = 0; qt < 2; qt++) {
    const bf16* qp = Q + (bh_s + qb + qt * 16 + lr) * 64 + quad * 8;
    qf[qt][0] = *(const short8*)qp;
    qf[qt][1] = *(const short8*)(qp + 32);
  }

  short8 ones;
#pragma unroll
  for (int i = 0; i < 8; i++) ones[i] = (short)0x3F80;

  const int rA = w * 16 + (lane >> 3), rB = rA + 8;
  const int c8 = lane & 7;
  const bf16* kA = Kg + (bh_s + rA) * 64 + ((c8 ^ (rA & 7)) << 3);
  const bf16* kB = Kg + (bh_s + rB) * 64 + ((c8 ^ (rB & 7)) << 3);
  const bf16* vA = Vt + ((long)bh * 64 + rA) * 4096 + ((c8 ^ (rA & 7)) << 3);
  const bf16* vB = Vt + ((long)bh * 64 + rB) * 4096 + ((c8 ^ (rB & 7)) << 3);
  const int ldsA = (w * 16) * 64 + lane * 8;       // elems; == base + lane*16B
  const int ldsB = ldsA + 8 * 64;

  const int cA = (quad * 8) ^ ((lr & 7) << 3);     // swizzled read col (elems)

  f32x4 lacc[2] = {};
  f32x4 Ot[4][2] = {};                             // O^T[d-tile][q-tile]

  auto stage = [&](int kc, int buf) {
    gl_lds16(kA + (long)kc * 64, &sK[buf][ldsA]);
    gl_lds16(kB + (long)kc * 64, &sK[buf][ldsB]);
    gl_lds16(vA + kc, &sV[buf][ldsA]);
    gl_lds16(vB + kc, &sV[buf][ldsB]);
  };

  auto compute = [&](int buf) {
    const bf16* Kb = sK[buf];
    const bf16* Vb = sV[buf];
    f32x4 st[4][2] = {};
    __builtin_amdgcn_s_setprio(1);
#pragma unroll
    for (int kt = 0; kt < 4; kt++) {
      const int rowb = (kt * 16 + lr) * 64;
      short8 kfa = *(const short8*)&Kb[rowb + cA];
      short8 kfb = *(const short8*)&Kb[rowb + (cA ^ 32)];
      st[kt][0] = MFMA(kfa, qf[0][0], st[kt][0]);
      st[kt][0] = MFMA(kfb, qf[0][1], st[kt][0]);
      st[kt][1] = MFMA(kfa, qf[1][0], st[kt][1]);
      st[kt][1] = MFMA(kfb, qf[1][1], st[kt][1]);
    }
    __builtin_amdgcn_s_setprio(0);

    short8 pf[2][2];
#pragma unroll
    for (int qt = 0; qt < 2; qt++) {
      float p[4][4];
#pragma unroll
      for (int kt = 0; kt < 4; kt++)
#pragma unroll
        for (int r = 0; r < 4; r++)
          p[kt][r] = EXP2(st[kt][qt][r]);
      unsigned u00 = cvt_pk(p[0][0], p[0][1]), u01 = cvt_pk(p[0][2], p[0][3]);
      unsigned u10 = cvt_pk(p[1][0], p[1][1]), u11 = cvt_pk(p[1][2], p[1][3]);
      unsigned u20 = cvt_pk(p[2][0], p[2][1]), u21 = cvt_pk(p[2][2], p[2][3]);
      unsigned u30 = cvt_pk(p[3][0], p[3][1]), u31 = cvt_pk(p[3][2], p[3][3]);
      // stage 1: lane5 <-> reg-bit (kt low bit)
      PSWAP32(u00, u10); PSWAP32(u01, u11);
      PSWAP32(u20, u30); PSWAP32(u21, u31);
      // stage 2: lane4 <-> reg-bit
      PSWAP16(u00, u10); PSWAP16(u01, u11);
      PSWAP16(u20, u30); PSWAP16(u21, u31);
      union { unsigned u[4]; short8 s8; } fa, fb;
      fa.u[0] = u00; fa.u[1] = u01; fa.u[2] = u10; fa.u[3] = u11;  // keys 0-31
      fb.u[0] = u20; fb.u[1] = u21; fb.u[2] = u30; fb.u[3] = u31;  // keys 32-63
      pf[qt][0] = fa.s8;
      pf[qt][1] = fb.s8;
    }

    __builtin_amdgcn_s_setprio(1);
#pragma unroll
    for (int dt = 0; dt < 4; dt++) {
      const int rowb = (dt * 16 + lr) * 64;
      short8 vfa = *(const short8*)&Vb[rowb + cA];
      short8 vfb = *(const short8*)&Vb[rowb + (cA ^ 32)];
      Ot[dt][0] = MFMA(vfa, pf[0][0], Ot[dt][0]);
      Ot[dt][0] = MFMA(vfb, pf[0][1], Ot[dt][0]);
      Ot[dt][1] = MFMA(vfa, pf[1][0], Ot[dt][1]);
      Ot[dt][1] = MFMA(vfb, pf[1][1], Ot[dt][1]);
    }
    lacc[0] = MFMA(ones, pf[0][0], lacc[0]);
    lacc[0] = MFMA(ones, pf[0][1], lacc[0]);
    lacc[1] = MFMA(ones, pf[1][0], lacc[1]);
    lacc[1] = MFMA(ones, pf[1][1], lacc[1]);
    __builtin_amdgcn_s_setprio(0);
  };

  stage(0, 0);
  for (int ci = 0; ci < nch; ci++) {
    __syncthreads();                       // chunk ci staged; prev reads done
    if (ci + 1 < nch) stage((ci + 1) * 64, (ci + 1) & 1);
    compute(ci & 1);
  }

#pragma unroll
  for (int qt = 0; qt < 2; qt++) {
    const float l = lacc[qt][0] - (float)npv;
    const float il = (l > 0.f) ? 1.f / l : 0.f;
    const int q = qb + qt * 16 + lr;
    bf16* cp = ctx + ((long)(b * 4096 + q)) * 768 + hh * 64 + quad * 4;
#pragma unroll
    for (int dt = 0; dt < 4; dt++) {
      short4v ov;
      ov.x = f2b(Ot[dt][qt][0] * il);
      ov.y = f2b(Ot[dt][qt][1] * il);
      ov.z = f2b(Ot[dt][qt][2] * il);
      ov.w = f2b(Ot[dt][qt][3] * il);
      *(short4v*)(cp + dt * 16) = ov;
    }
  }
}

// ---------------------------------------------------------------------------
extern "C" void kernel_launch(void* const* d_in, const int* in_sizes, int n_in,
                              void* d_out, int out_size, void* d_ws, size_t ws_size,
                              hipStream_t stream)
{
  (void)in_sizes; (void)n_in; (void)out_size; (void)ws_size;
  const float* x    = (const float*)d_in[0];
  const int*   mask = (const int*)  d_in[1];
  const float* wq = (const float*)d_in[2];  const float* bq = (const float*)d_in[3];
  const float* wk = (const float*)d_in[4];  const float* bk = (const float*)d_in[5];
  const float* wv = (const float*)d_in[6];  const float* bv = (const float*)d_in[7];
  const float* wo = (const float*)d_in[8];  const float* bo = (const float*)d_in[9];
  const float* w1 = (const float*)d_in[10]; const float* b1 = (const float*)d_in[11];
  const float* w2 = (const float*)d_in[12]; const float* b2 = (const float*)d_in[13];
  const float* alpha1 = (const float*)d_in[14]; const float* beta1 = (const float*)d_in[15];
  const float* alpha2 = (const float*)d_in[16]; const float* beta2 = (const float*)d_in[17];
  float* out = (float*)d_out;

  const long WSZ = (long)768 * 768 * 2;
  const long W1SZ = (long)3072 * 768 * 2;
  const long SZB = (long)8192 * 768 * 2;
  char* ws = (char*)d_ws;
  bf16* wqkvb = (bf16*)(ws);
  bf16* wob = (bf16*)(ws + 3 * WSZ);
  bf16* w1b = (bf16*)(ws + 4 * WSZ);
  bf16* w2b = (bf16*)(ws + 4 * WSZ + W1SZ);
  char* aux = ws + 4 * WSZ + 2 * W1SZ;
  float* bqkv   = (float*)(aux);
  int*   pos_g  = (int*)(aux + 16384);
  int*   nch_g  = (int*)(aux + 81920);
  const long BASE = 16l << 20;
  bf16* h   = (bf16*)(ws + BASE);
  bf16* qws = (bf16*)(ws + BASE + 1 * SZB);
  bf16* kcw = (bf16*)(ws + BASE + 2 * SZB);
  bf16* vtc = (bf16*)(ws + BASE + 3 * SZB);
  bf16* ctx = (bf16*)(ws + BASE + 4 * SZB);
  bf16* x1  = (bf16*)(ws + BASE + 5 * SZB);
  bf16* ff  = qws;

  dim3 blk(256);

  hipLaunchKernelGGL(prep_all, dim3(6914), blk, 0, stream,
                     wq, wk, wv, wo, w1, w2, bq, bk, bv, mask,
                     wqkvb, wob, w1b, w2b, bqkv, pos_g, nch_g, kcw, vtc);

  hipLaunchKernelGGL((ln_kernel<float>), dim3(8192), blk, 0, stream, x, h, alpha1, beta1);
  hipLaunchKernelGGL(gemm_qkv, dim3(64, 18), blk, 0, stream, h, wqkvb, bqkv, pos_g, qws, kcw, vtc);
  hipLaunchKernelGGL(attn_kernel, dim3(32, 24), blk, 0, stream, qws, kcw, vtc, nch_g, ctx);
  // O-proj: TM=64, BK=64 (12 K-steps, LDS 48KB = 3 resident = grid limit)
  hipLaunchKernelGGL((gemm_bt<4, 64, 64, float, bf16>), dim3(128, 6), blk, 0, stream, ctx, wob, bo, x, x1, 8192, 768, 768);
  hipLaunchKernelGGL((ln_kernel<bf16>), dim3(8192), blk, 0, stream, x1, h, alpha2, beta2);
  // FFN1: TM=128, BK=32 (unchanged: BK=64 would cost occupancy)
  hipLaunchKernelGGL((gemm_bt<1, 128, 32, float, bf16>), dim3(64, 24), blk, 0, stream, h, w1b, b1, (const float*)nullptr, ff, 8192, 3072, 768);
  // FFN2: TM=64, BK=64 (K=3072: 96 -> 48 K-steps/barriers)
  hipLaunchKernelGGL((gemm_bt<4, 64, 64, bf16, float>), dim3(128, 6), blk, 0, stream, ff, w2b, b2, x1, out, 8192, 768, 3072);
}